// Round 2
// baseline (286.625 us; speedup 1.0000x reference)
//
#include <hip/hip_runtime.h>

typedef __bf16 bf16x8 __attribute__((ext_vector_type(8)));
typedef float  f32x4  __attribute__((ext_vector_type(4)));

__device__ __forceinline__ unsigned short f2bf(float f) {
  unsigned int u = __builtin_bit_cast(unsigned int, f);
  u = u + 0x7fffu + ((u >> 16) & 1u);
  return (unsigned short)(u >> 16);
}

// ws layout (ushort elements):
//   W1b [256][256] @ 0        (row-major, N x K)
//   W2b [256][256] @ 65536
//   W3b [256][640] @ 131072
//   W4b [16][256]  @ 294912   (rows 8..15 zeroed)
#define O_W2 65536
#define O_W3 131072
#define O_W4 294912
#define N_PREP 299008

__global__ void prep_kernel(const float* __restrict__ W1, const float* __restrict__ W2,
                            const float* __restrict__ W3, const float* __restrict__ W4,
                            unsigned short* __restrict__ ws) {
  int id = blockIdx.x * 256 + threadIdx.x;
  if (id < O_W2) {
    ws[id] = f2bf(W1[id]);
  } else if (id < O_W3) {
    ws[id] = f2bf(W2[id - O_W2]);
  } else if (id < O_W4) {
    ws[id] = f2bf(W3[id - O_W3]);
  } else if (id < N_PREP) {
    int t = id - O_W4;
    ws[id] = (t < 2048) ? f2bf(W4[t]) : (unsigned short)0;
  }
}

// xxx: 64 rows x 640 cols bf16, stride 640 (80 KB exactly -> 2 blocks/CU).
// XOR swizzle on element index (bits 3..5 ^= row&7) = byte bits 4..6:
// per-16-lane beat, the 8 distinct rows map to 8 distinct 4-bank groups.
#define SX(r, c) ((r) * 640 + ((c) ^ (((r) & 7) << 3)))

#define MFMA __builtin_amdgcn_mfma_f32_16x16x32_bf16

__global__ __launch_bounds__(512, 4) void actor_kernel(
    const float* __restrict__ state,
    const float* __restrict__ b1, const float* __restrict__ b2,
    const float* __restrict__ b3, const float* __restrict__ b4,
    const unsigned short* __restrict__ wsb,
    float* __restrict__ out)
{
  // xxx row r: cols [0,256)   = h_i (later overwritten by y), cols [256,640) = state row r as bf16
  __shared__ __align__(16) unsigned short xxx[64 * 640];

  const int tid  = threadIdx.x;
  const int w    = tid >> 6;     // wave 0..7
  const int lane = tid & 63;
  const int lr   = lane & 15;
  const int lg   = lane >> 4;
  const long b0  = (long)blockIdx.x * 64;

  // ---- Phase 0: stage 64 state rows (64x384 f32) into xxx cols 256..639 as bf16 ----
  {
    const float4* sp = (const float4*)(state + b0 * 384);
    #pragma unroll
    for (int t = 0; t < 12; ++t) {
      int f = tid + t * 512;             // float4 index, < 6144
      float4 v = sp[f];
      int r   = f / 96;
      int rem = f - r * 96;
      int i   = rem >> 5;
      int k4  = (rem & 31) << 2;
      ushort4 u;
      u.x = f2bf(v.x); u.y = f2bf(v.y); u.z = f2bf(v.z); u.w = f2bf(v.w);
      *(ushort4*)&xxx[SX(r, 256 + i * 128 + k4)] = u;
    }
  }
  __syncthreads();

  // ---- GEMM1: agents(128x256) @ {W1,W2}^T + bias, relu, softmax combine -> h cols [0,256) ----
  // M split across waves (wm: 64 agent rows), N: 2 passes x (32 H-cols paired with 32 E-cols).
  const int wm = w >> 2;   // 0..1
  const int wn = w & 3;    // 0..3
  #pragma unroll
  for (int sc = 0; sc < 2; ++sc) {
    const int nb = wn * 64 + sc * 32;   // column base for this pass (both H and E)
    f32x4 acc[4][4];                    // [rt][c]: c0,c1 = H cols nb+0/+16; c2,c3 = E cols nb+0/+16
    #pragma unroll
    for (int rt = 0; rt < 4; ++rt)
      #pragma unroll
      for (int c = 0; c < 4; ++c)
        acc[rt][c] = (f32x4){0.f, 0.f, 0.f, 0.f};

    const unsigned short* w1p = wsb + (nb + lr) * 256 + lg * 8;
    const unsigned short* w2p = wsb + O_W2 + (nb + lr) * 256 + lg * 8;
    bf16x8 bh0 = *(const bf16x8*)(w1p);
    bf16x8 bh1 = *(const bf16x8*)(w1p + 16 * 256);
    bf16x8 be0 = *(const bf16x8*)(w2p);
    bf16x8 be1 = *(const bf16x8*)(w2p + 16 * 256);
    const float bv1a = b1[nb + lr], bv1b = b1[nb + 16 + lr];
    const float bv2a = b2[nb + lr], bv2b = b2[nb + 16 + lr];

    #pragma unroll
    for (int ks = 0; ks < 8; ++ks) {
      bf16x8 nh0, nh1, ne0, ne1;
      if (ks < 7) {
        nh0 = *(const bf16x8*)(w1p + (ks + 1) * 32);
        nh1 = *(const bf16x8*)(w1p + 16 * 256 + (ks + 1) * 32);
        ne0 = *(const bf16x8*)(w2p + (ks + 1) * 32);
        ne1 = *(const bf16x8*)(w2p + 16 * 256 + (ks + 1) * 32);
      }
      const int colo = (ks < 4) ? (256 + ks * 32 + lg * 8)
                                : (384 + (ks - 4) * 32 + lg * 8);
      const int po   = (ks >= 4) ? ((lr & 1) << 7) : 0;
      #pragma unroll
      for (int rt = 0; rt < 4; ++rt) {
        const int r = wm * 32 + rt * 8 + (lr >> 1);
        bf16x8 a = *(const bf16x8*)&xxx[SX(r, colo + po)];
        acc[rt][0] = MFMA(a, bh0, acc[rt][0], 0, 0, 0);
        acc[rt][1] = MFMA(a, bh1, acc[rt][1], 0, 0, 0);
        acc[rt][2] = MFMA(a, be0, acc[rt][2], 0, 0, 0);
        acc[rt][3] = MFMA(a, be1, acc[rt][3], 0, 0, 0);
      }
      if (ks < 7) { bh0 = nh0; bh1 = nh1; be0 = ne0; be1 = ne1; }
    }

    // combine: D rows (lg*4+reg) in each 16-tile; reg = 2*pr+p -> state row, agent p
    #pragma unroll
    for (int rt = 0; rt < 4; ++rt) {
      #pragma unroll
      for (int pr = 0; pr < 2; ++pr) {
        const int r = wm * 32 + rt * 8 + lg * 2 + pr;
        {
          float h0 = fmaxf(acc[rt][0][2 * pr + 0] + bv1a, 0.f);
          float h1 = fmaxf(acc[rt][0][2 * pr + 1] + bv1a, 0.f);
          float e0 = fmaxf(acc[rt][2][2 * pr + 0] + bv2a, 0.f);
          float e1 = fmaxf(acc[rt][2][2 * pr + 1] + bv2a, 0.f);
          float a0 = 1.0f / (1.0f + __expf(e1 - e0));
          xxx[SX(r, nb + lr)] = f2bf(h1 + a0 * (h0 - h1));
        }
        {
          float h0 = fmaxf(acc[rt][1][2 * pr + 0] + bv1b, 0.f);
          float h1 = fmaxf(acc[rt][1][2 * pr + 1] + bv1b, 0.f);
          float e0 = fmaxf(acc[rt][3][2 * pr + 0] + bv2b, 0.f);
          float e1 = fmaxf(acc[rt][3][2 * pr + 1] + bv2b, 0.f);
          float a0 = 1.0f / (1.0f + __expf(e1 - e0));
          xxx[SX(r, nb + 16 + lr)] = f2bf(h1 + a0 * (h0 - h1));
        }
      }
    }
  }
  __syncthreads();

  // ---- GEMM3: xxx(64x640) @ W3^T + b3, relu. M split 2 x N split 4 (64 cols/wave) ----
  const int wm3 = w & 1;    // rows [wm3*32, +32)
  const int wn3 = w >> 1;   // cols [wn3*64, +64)
  f32x4 acc3[2][4];
  #pragma unroll
  for (int rt = 0; rt < 2; ++rt)
    #pragma unroll
    for (int nt = 0; nt < 4; ++nt)
      acc3[rt][nt] = (f32x4){0.f, 0.f, 0.f, 0.f};

  {
    const unsigned short* w3p = wsb + O_W3 + (wn3 * 64 + lr) * 640 + lg * 8;
    bf16x8 c0 = *(const bf16x8*)(w3p);
    bf16x8 c1 = *(const bf16x8*)(w3p + 16 * 640);
    bf16x8 c2 = *(const bf16x8*)(w3p + 32 * 640);
    bf16x8 c3 = *(const bf16x8*)(w3p + 48 * 640);
    for (int ks = 0; ks < 20; ++ks) {
      bf16x8 d0, d1, d2, d3;
      if (ks < 19) {
        d0 = *(const bf16x8*)(w3p + (ks + 1) * 32);
        d1 = *(const bf16x8*)(w3p + 16 * 640 + (ks + 1) * 32);
        d2 = *(const bf16x8*)(w3p + 32 * 640 + (ks + 1) * 32);
        d3 = *(const bf16x8*)(w3p + 48 * 640 + (ks + 1) * 32);
      }
      #pragma unroll
      for (int rt = 0; rt < 2; ++rt) {
        bf16x8 a = *(const bf16x8*)&xxx[SX(wm3 * 32 + rt * 16 + lr, ks * 32 + lg * 8)];
        acc3[rt][0] = MFMA(a, c0, acc3[rt][0], 0, 0, 0);
        acc3[rt][1] = MFMA(a, c1, acc3[rt][1], 0, 0, 0);
        acc3[rt][2] = MFMA(a, c2, acc3[rt][2], 0, 0, 0);
        acc3[rt][3] = MFMA(a, c3, acc3[rt][3], 0, 0, 0);
      }
      if (ks < 19) { c0 = d0; c1 = d1; c2 = d2; c3 = d3; }
    }
  }
  const float bv3_0 = b3[wn3 * 64 + lr];
  const float bv3_1 = b3[wn3 * 64 + 16 + lr];
  const float bv3_2 = b3[wn3 * 64 + 32 + lr];
  const float bv3_3 = b3[wn3 * 64 + 48 + lr];
  __syncthreads();   // everyone done reading h region before y overwrites it

  // write y (bf16) into cols [0,256)
  #pragma unroll
  for (int rt = 0; rt < 2; ++rt) {
    #pragma unroll
    for (int reg = 0; reg < 4; ++reg) {
      const int row = wm3 * 32 + rt * 16 + lg * 4 + reg;
      xxx[SX(row, wn3 * 64 + lr)]      = f2bf(fmaxf(acc3[rt][0][reg] + bv3_0, 0.f));
      xxx[SX(row, wn3 * 64 + 16 + lr)] = f2bf(fmaxf(acc3[rt][1][reg] + bv3_1, 0.f));
      xxx[SX(row, wn3 * 64 + 32 + lr)] = f2bf(fmaxf(acc3[rt][2][reg] + bv3_2, 0.f));
      xxx[SX(row, wn3 * 64 + 48 + lr)] = f2bf(fmaxf(acc3[rt][3][reg] + bv3_3, 0.f));
    }
  }
  __syncthreads();

  // ---- GEMM4: y(64x256) @ W4b^T (16 rows, 8 valid), + b4, tanh -> out ----
  if (w < 4) {
    f32x4 acc4 = (f32x4){0.f, 0.f, 0.f, 0.f};
    const unsigned short* w4p = wsb + O_W4 + lr * 256 + lg * 8;
    #pragma unroll
    for (int ks = 0; ks < 8; ++ks) {
      bf16x8 a = *(const bf16x8*)&xxx[SX(w * 16 + lr, ks * 32 + lg * 8)];
      bf16x8 b = *(const bf16x8*)(w4p + ks * 32);
      acc4 = MFMA(a, b, acc4, 0, 0, 0);
    }
    if (lr < 8) {
      const float b4v = b4[lr];
      #pragma unroll
      for (int reg = 0; reg < 4; ++reg) {
        float x = acc4[reg] + b4v;
        float z = __expf(-2.f * fabsf(x));
        float t = (1.f - z) / (1.f + z);
        long row = b0 + w * 16 + lg * 4 + reg;
        out[row * 8 + lr] = copysignf(t, x);
      }
    }
  }
}

extern "C" void kernel_launch(void* const* d_in, const int* in_sizes, int n_in,
                              void* d_out, int out_size, void* d_ws, size_t ws_size,
                              hipStream_t stream) {
  const float* state = (const float*)d_in[0];
  const float* W1 = (const float*)d_in[1];
  const float* b1 = (const float*)d_in[2];
  const float* W2 = (const float*)d_in[3];
  const float* b2 = (const float*)d_in[4];
  const float* W3 = (const float*)d_in[5];
  const float* b3 = (const float*)d_in[6];
  const float* W4 = (const float*)d_in[7];
  const float* b4 = (const float*)d_in[8];

  unsigned short* wsb = (unsigned short*)d_ws;

  prep_kernel<<<(N_PREP + 255) / 256, 256, 0, stream>>>(W1, W2, W3, W4, wsb);
  actor_kernel<<<1024, 512, 0, stream>>>(state, b1, b2, b3, b4, wsb, (float*)d_out);
}